// Round 10
// baseline (1211.514 us; speedup 1.0000x reference)
//
#include <hip/hip_runtime.h>
#include <hip/hip_bf16.h>
#include <math.h>

typedef __attribute__((ext_vector_type(8))) short short8;
typedef __attribute__((ext_vector_type(4))) short sv4;
typedef __attribute__((ext_vector_type(4))) float f32x4;
typedef unsigned int u32;

#define BT_ 384
#define N_ 716
#define C_ 256
#define H_ 8
#define D_ 32
#define MROWS (BT_ * N_)   /* 274944 */
#define NT_ (MROWS / 64)   /* 4296 row-tiles of 64 */
#define SCALE_ 0.17677669529663687f  /* 32^-0.5 */
#define INVN_ (1.0f / 716.0f)

// ---------------------------------------------------------------------------
// Assemble bf16 weight matrices + fused qkv bias. Wqkv_b[768][256], Wo_b[256][256]
// ---------------------------------------------------------------------------
__global__ void prep_weights(const float* __restrict__ Wq, const float* __restrict__ bq,
                             const float* __restrict__ Wk, const float* __restrict__ bk,
                             const float* __restrict__ Wv, const float* __restrict__ bv,
                             const float* __restrict__ Wo,
                             __hip_bfloat16* __restrict__ wqkv, float* __restrict__ bqkv,
                             __hip_bfloat16* __restrict__ wo) {
    int idx = blockIdx.x * 256 + threadIdx.x;
    if (idx < 768 * 256) {
        int o = idx >> 8, c = idx & 255;
        const float* W = (o < 256) ? Wq : ((o < 512) ? Wk : Wv);
        int oo = o & 255;
        wqkv[idx] = __float2bfloat16(W[oo * 256 + c]);
    }
    if (idx < 256 * 256) wo[idx] = __float2bfloat16(Wo[idx]);
    if (idx < 768) bqkv[idx] = (idx < 256) ? bq[idx] : ((idx < 512) ? bk[idx - 256] : bv[idx - 512]);
}

// ---------------------------------------------------------------------------
// x fp32 -> bf16 (vectorized float4/short4), plus per-(bt,channel) col sums
// grid (384, 4), block 256.
// ---------------------------------------------------------------------------
__global__ __launch_bounds__(256)
void convert_x(const float* __restrict__ x, __hip_bfloat16* __restrict__ xb,
               float* __restrict__ msum) {
    int bt = blockIdx.x, chunk = blockIdx.y;
    int t = threadIdx.x;
    int c4 = (t & 63) * 4;
    int r0 = t >> 6;
    size_t base = ((size_t)bt * N_ + (size_t)chunk * 179) * C_;
    float s0 = 0.f, s1 = 0.f, s2 = 0.f, s3 = 0.f;
    for (int r = r0; r < 179; r += 4) {
        float4 f = *(const float4*)&x[base + (size_t)r * C_ + c4];
        union { sv4 v; __hip_bfloat16 h[4]; } u;
        u.h[0] = __float2bfloat16(f.x);
        u.h[1] = __float2bfloat16(f.y);
        u.h[2] = __float2bfloat16(f.z);
        u.h[3] = __float2bfloat16(f.w);
        *(sv4*)&xb[base + (size_t)r * C_ + c4] = u.v;
        s0 += f.x; s1 += f.y; s2 += f.z; s3 += f.w;
    }
    atomicAdd(&msum[bt * C_ + c4 + 0], s0);
    atomicAdd(&msum[bt * C_ + c4 + 1], s1);
    atomicAdd(&msum[bt * C_ + c4 + 2], s2);
    atomicAdd(&msum[bt * C_ + c4 + 3], s3);
}

// ---------------------------------------------------------------------------
// Grouped 2-layer MLP -> per-channel 3-tap conv weights rw[bt][768]
// ---------------------------------------------------------------------------
__global__ __launch_bounds__(256)
void mlp_rw(const float* __restrict__ msum, const float* __restrict__ w1,
            const float* __restrict__ b1, const float* __restrict__ w2,
            const float* __restrict__ b2, float* __restrict__ rw) {
    int bt = blockIdx.x;
    int t = threadIdx.x;
    __shared__ float m_l[256];
    __shared__ float h1_l[256];
    m_l[t] = msum[bt * 256 + t] * INVN_;
    __syncthreads();
    int g = t >> 5;
    float a = b1[t];
    #pragma unroll
    for (int i = 0; i < 32; ++i) a += m_l[g * 32 + i] * w1[t * 32 + i];
    h1_l[t] = 0.5f * a * (1.0f + erff(a * 0.70710678118654752f));
    __syncthreads();
    for (int o = t; o < 768; o += 256) {
        int gg = o / 96;
        float s = b2[o];
        #pragma unroll
        for (int i = 0; i < 32; ++i) s += h1_l[gg * 32 + i] * w2[o * 32 + i];
        rw[bt * 768 + o] = s;
    }
}

// ---------------------------------------------------------------------------
// gemm_qkv: A-read-once, B-streamed-from-L2. Block = 512 thr (8 waves) owns
// row-stripes rt = bid, bid+256, ... with ALL 768 output cols.
// Wave w's 6 col-frags at cols {w*16 + c*128}. A reg->LDS staged (XOR swz,
// 2-buffer); B per-ks 1-deep prefetch (#pragma unroll 1 pair loop).
// Epilogue: 6 chunks of 128 cols through LDS, coalesced short8 stores.
// grid 256, block 512.
// ---------------------------------------------------------------------------
__global__ __launch_bounds__(512, 2)
void gemm_qkv(const __hip_bfloat16* __restrict__ A, const __hip_bfloat16* __restrict__ Bm,
              const float* __restrict__ bias, __hip_bfloat16* __restrict__ outp) {
    __shared__ __align__(16) __hip_bfloat16 T[2][64 * 256];   // 64 KB
    __shared__ __align__(16) __hip_bfloat16 Cs[64 * 136];     // 17 KB
    const int bid = blockIdx.x;
    const int tid = threadIdx.x;
    const int lane = tid & 63;
    const int w = tid >> 6;                 // wave 0..7
    const int l15 = lane & 15, lq = lane >> 4;
    const int xr = l15 & 7;                 // row&7 for af reads (m*16 ≡ 0 mod 8)
    const int sc = tid & 31;                // 16B slot within 512B row
    const int rg4 = (tid >> 5) * 4;         // staging row group (4 rows)
    const int wcol = w * 16 + l15;          // frag col within each 128-chunk

    short8 aload[4];
    auto loadA4 = [&](int rt) {
        #pragma unroll
        for (int i = 0; i < 4; ++i)
            aload[i] = *(const short8*)&A[((size_t)rt * 64 + rg4 + i) * 256 + sc * 8];
    };
    auto dsWriteA = [&](int buf) {
        #pragma unroll
        for (int i = 0; i < 4; ++i) {
            int row = rg4 + i;
            *(short8*)&T[buf][row * 256 + ((sc ^ (row & 7)) * 8)] = aload[i];
        }
    };

    float biasr[6];
    #pragma unroll
    for (int c = 0; c < 6; ++c) biasr[c] = bias[c * 128 + wcol];

    // prologue: tile0 into buf0; prefetch tile1 into regs
    loadA4(bid);
    dsWriteA(0);
    loadA4(bid + 256);
    asm volatile("s_waitcnt lgkmcnt(0)" ::: "memory");
    __builtin_amdgcn_s_barrier();

    int t = 0;
    for (int rt = bid; rt < NT_; rt += 256, ++t) {
        const int buf = t & 1;
        // stage tile t+1 (data already in regs), prefetch tile t+2
        if (rt + 256 < NT_) dsWriteA(buf ^ 1);
        if (rt + 512 < NT_) loadA4(rt + 512);

        const __hip_bfloat16* Tb = &T[buf][0];
        f32x4 acc[4][6] = {};
        short8 bfA[6], bfB[6];
        auto loadB6 = [&](short8* dst, int ks) {
            #pragma unroll
            for (int c = 0; c < 6; ++c)
                dst[c] = *(const short8*)&Bm[(size_t)(c * 128 + wcol) * 256 + ks * 32 + lq * 8];
        };
        auto mfma6 = [&](const short8* bfv, int ks) {
            short8 af[4];
            int so = ((ks * 4 + lq) ^ xr) * 8;
            #pragma unroll
            for (int m = 0; m < 4; ++m)
                af[m] = *(const short8*)&Tb[(m * 16 + l15) * 256 + so];
            #pragma unroll
            for (int m = 0; m < 4; ++m)
                #pragma unroll
                for (int c = 0; c < 6; ++c)
                    acc[m][c] = __builtin_amdgcn_mfma_f32_16x16x32_bf16(af[m], bfv[c], acc[m][c], 0, 0, 0);
        };

        loadB6(bfA, 0);
        #pragma unroll 1
        for (int kp = 0; kp < 4; ++kp) {
            loadB6(bfB, kp * 2 + 1);
            mfma6(bfA, kp * 2);
            if (kp < 3) loadB6(bfA, kp * 2 + 2);
            mfma6(bfB, kp * 2 + 1);
        }

        // epilogue: 6 chunks of 128 cols via LDS, coalesced stores
        #pragma unroll 1
        for (int c = 0; c < 6; ++c) {
            #pragma unroll
            for (int m = 0; m < 4; ++m)
                #pragma unroll
                for (int j = 0; j < 4; ++j)
                    Cs[(m * 16 + lq * 4 + j) * 136 + wcol] =
                        __float2bfloat16(acc[m][c][j] + biasr[c]);
            asm volatile("s_waitcnt lgkmcnt(0)" ::: "memory");
            __builtin_amdgcn_s_barrier();
            int row = tid >> 3, s = tid & 7;
            __hip_bfloat16* og = outp + ((size_t)rt * 64 + row) * 768 + c * 128 + s * 16;
            short8 v0 = *(const short8*)&Cs[row * 136 + s * 16];
            short8 v1 = *(const short8*)&Cs[row * 136 + s * 16 + 8];
            *(short8*)&og[0] = v0;
            *(short8*)&og[8] = v1;
            __builtin_amdgcn_s_barrier();
        }
    }
}

// ---------------------------------------------------------------------------
// gemm_out: A-read-once, B fully register-resident (256 cols, 16 frags).
// Same staging/epilogue structure; fp32 output, 2 chunks of 128 cols.
// grid 256, block 512.
// ---------------------------------------------------------------------------
__global__ __launch_bounds__(512, 2)
void gemm_out(const __hip_bfloat16* __restrict__ A, const __hip_bfloat16* __restrict__ Bm,
              const float* __restrict__ bias, float* __restrict__ outp) {
    __shared__ __align__(16) __hip_bfloat16 T[2][64 * 256];   // 64 KB
    __shared__ __align__(16) float Csf[64 * 132];             // 33.8 KB
    const int bid = blockIdx.x;
    const int tid = threadIdx.x;
    const int lane = tid & 63;
    const int w = tid >> 6;
    const int l15 = lane & 15, lq = lane >> 4;
    const int xr = l15 & 7;
    const int sc = tid & 31;
    const int rg4 = (tid >> 5) * 4;
    const int wcol = w * 16 + l15;

    short8 aload[4];
    auto loadA4 = [&](int rt) {
        #pragma unroll
        for (int i = 0; i < 4; ++i)
            aload[i] = *(const short8*)&A[((size_t)rt * 64 + rg4 + i) * 256 + sc * 8];
    };
    auto dsWriteA = [&](int buf) {
        #pragma unroll
        for (int i = 0; i < 4; ++i) {
            int row = rg4 + i;
            *(short8*)&T[buf][row * 256 + ((sc ^ (row & 7)) * 8)] = aload[i];
        }
    };

    // B fully in registers: 2 chunks x 8 ks
    short8 bf[2][8];
    #pragma unroll
    for (int c = 0; c < 2; ++c)
        #pragma unroll
        for (int ks = 0; ks < 8; ++ks)
            bf[c][ks] = *(const short8*)&Bm[(size_t)(c * 128 + wcol) * 256 + ks * 32 + lq * 8];
    float biasr[2];
    #pragma unroll
    for (int c = 0; c < 2; ++c) biasr[c] = bias[c * 128 + wcol];

    loadA4(bid);
    dsWriteA(0);
    loadA4(bid + 256);
    asm volatile("s_waitcnt lgkmcnt(0)" ::: "memory");
    __builtin_amdgcn_s_barrier();

    int t = 0;
    for (int rt = bid; rt < NT_; rt += 256, ++t) {
        const int buf = t & 1;
        if (rt + 256 < NT_) dsWriteA(buf ^ 1);
        if (rt + 512 < NT_) loadA4(rt + 512);

        const __hip_bfloat16* Tb = &T[buf][0];
        f32x4 acc[4][2] = {};
        #pragma unroll
        for (int ks = 0; ks < 8; ++ks) {
            short8 af[4];
            int so = ((ks * 4 + lq) ^ xr) * 8;
            #pragma unroll
            for (int m = 0; m < 4; ++m)
                af[m] = *(const short8*)&Tb[(m * 16 + l15) * 256 + so];
            #pragma unroll
            for (int m = 0; m < 4; ++m)
                #pragma unroll
                for (int c = 0; c < 2; ++c)
                    acc[m][c] = __builtin_amdgcn_mfma_f32_16x16x32_bf16(af[m], bf[c][ks], acc[m][c], 0, 0, 0);
        }

        #pragma unroll 1
        for (int c = 0; c < 2; ++c) {
            #pragma unroll
            for (int m = 0; m < 4; ++m)
                #pragma unroll
                for (int j = 0; j < 4; ++j)
                    Csf[(m * 16 + lq * 4 + j) * 132 + wcol] = acc[m][c][j] + biasr[c];
            asm volatile("s_waitcnt lgkmcnt(0)" ::: "memory");
            __builtin_amdgcn_s_barrier();
            int row = tid >> 3, s = tid & 7;
            float* og = outp + ((size_t)rt * 64 + row) * 256 + c * 128;
            #pragma unroll
            for (int i = 0; i < 4; ++i) {
                int col = s * 4 + i * 32;
                *(float4*)&og[col] = *(const float4*)&Csf[row * 132 + col];
            }
            __builtin_amdgcn_s_barrier();
        }
    }
}

// ---------------------------------------------------------------------------
// MFMA reduce_kv (unchanged from R8): one block per bt, 8 waves = 8 heads.
// ---------------------------------------------------------------------------
__global__ __launch_bounds__(512, 2)
void reduce_kv(const __hip_bfloat16* __restrict__ qkv, __hip_bfloat16* __restrict__ kv2t,
               float* __restrict__ vmeanb) {
    __shared__ __align__(16) __hip_bfloat16 T[512 * 64];   // 64 KB
    const int bt = blockIdx.x;
    const int tid = threadIdx.x;
    const int lane = tid & 63;
    const int h = tid >> 6;
    const int l15 = lane & 15, lq = lane >> 4;
    const int co = tid >> 3;
    const int np3 = tid & 7;
    const size_t rowbase = (size_t)bt * N_;

    union S8 { short8 v; unsigned short u[8]; };
    const short8 zero8 = {0, 0, 0, 0, 0, 0, 0, 0};

    auto issue_loads = [&](int n0, S8* Aq, S8* Bq) {
        #pragma unroll
        for (int s = 0; s < 4; ++s) {
            int n = n0 + 2 * (np3 + 8 * s);
            Aq[s].v = (n < N_)     ? *(const short8*)&qkv[(rowbase + n) * 768 + 256 + co * 8] : zero8;
            Bq[s].v = (n + 1 < N_) ? *(const short8*)&qkv[(rowbase + n + 1) * 768 + 256 + co * 8] : zero8;
        }
    };
    auto write_lds = [&](S8* Aq, S8* Bq) {
        #pragma unroll
        for (int s = 0; s < 4; ++s) {
            int r = 2 * (np3 + 8 * s);
            int slotbase = ((r >> 3));
            #pragma unroll
            for (int j = 0; j < 8; ++j) {
                int c = co * 8 + j;
                u32 wv = (u32)Aq[s].u[j] | ((u32)Bq[s].u[j] << 16);
                int off = c * 64 + ((slotbase ^ (c & 7)) << 3) + (r & 7);
                *(u32*)&T[off] = wv;
            }
        }
    };

    S8 bufA[4], bufB[4], nxtA[4], nxtB[4];
    issue_loads(0, bufA, bufB);

    f32x4 acc[2][2] = {};
    f32x4 acck[2] = {};
    f32x4 accv[2] = {};
    S8 ones;
    #pragma unroll
    for (int j = 0; j < 8; ++j) ones.u[j] = 0x3F80;   // bf16 1.0

    for (int chunk = 0; chunk < 12; ++chunk) {
        if (chunk < 11) issue_loads((chunk + 1) * 64, nxtA, nxtB);
        write_lds(bufA, bufB);
        __syncthreads();
        #pragma unroll
        for (int nc = 0; nc < 2; ++nc) {
            short8 af[2], bfr[2];
            int slot = nc * 4 + lq;
            #pragma unroll
            for (int dh = 0; dh < 2; ++dh) {
                int c = h * 32 + dh * 16 + l15;
                af[dh] = *(const short8*)&T[c * 64 + ((slot ^ (c & 7)) << 3)];
            }
            #pragma unroll
            for (int eh = 0; eh < 2; ++eh) {
                int c = 256 + h * 32 + eh * 16 + l15;
                bfr[eh] = *(const short8*)&T[c * 64 + ((slot ^ (c & 7)) << 3)];
            }
            #pragma unroll
            for (int dh = 0; dh < 2; ++dh)
                #pragma unroll
                for (int eh = 0; eh < 2; ++eh)
                    acc[dh][eh] = __builtin_amdgcn_mfma_f32_16x16x32_bf16(af[dh], bfr[eh], acc[dh][eh], 0, 0, 0);
            #pragma unroll
            for (int dh = 0; dh < 2; ++dh)
                acck[dh] = __builtin_amdgcn_mfma_f32_16x16x32_bf16(af[dh], ones.v, acck[dh], 0, 0, 0);
            #pragma unroll
            for (int eh = 0; eh < 2; ++eh)
                accv[eh] = __builtin_amdgcn_mfma_f32_16x16x32_bf16(ones.v, bfr[eh], accv[eh], 0, 0, 0);
        }
        __syncthreads();
        #pragma unroll
        for (int s = 0; s < 4; ++s) { bufA[s] = nxtA[s]; bufB[s] = nxtB[s]; }
    }

    const int bh = bt * 8 + h;
    #pragma unroll
    for (int eh = 0; eh < 2; ++eh) {
        int e = eh * 16 + l15;
        float vme = accv[eh][0] * INVN_;
        #pragma unroll
        for (int dh = 0; dh < 2; ++dh) {
            union { sv4 v; __hip_bfloat16 x[4]; } o;
            #pragma unroll
            for (int j = 0; j < 4; ++j) {
                float km = acck[dh][j] * INVN_;
                float val = acc[dh][eh][j] * (SCALE_ * INVN_) - SCALE_ * km * vme;
                o.x[j] = __float2bfloat16(val);
            }
            *(sv4*)&kv2t[(size_t)bh * 1024 + e * 32 + dh * 16 + lq * 4] = o.v;
        }
        if (lq == 0) vmeanb[bh * 32 + e] = vme;
    }
}

// ---------------------------------------------------------------------------
// fuse_z2 (unchanged)
// ---------------------------------------------------------------------------
__global__ __launch_bounds__(256)
void fuse_z2(const __hip_bfloat16* __restrict__ qkv, const __hip_bfloat16* __restrict__ kv2t,
             const float* __restrict__ vmeanb, const float* __restrict__ rw,
             __hip_bfloat16* __restrict__ Z) {
    __shared__ __align__(16) __hip_bfloat16 attn[64][256];
    __shared__ __align__(16) __hip_bfloat16 kvl[8192];
    int bt = blockIdx.x;
    int n0 = blockIdx.y * 64;
    int rows = (N_ - n0 < 64) ? (N_ - n0) : 64;
    int t = threadIdx.x;
    const size_t rowbase = (size_t)bt * N_;

    {
        const __hip_bfloat16* src = kv2t + (size_t)bt * 8192;
        #pragma unroll
        for (int i = 0; i < 4; ++i) {
            int off = (t + i * 256) * 8;
            *(short8*)&kvl[off] = *(const short8*)&src[off];
        }
    }
    __syncthreads();

    {
        int lane = t & 63, wave = t >> 6;
        int l15 = lane & 15, lq = lane >> 4;
        int r0 = wave * 16;
        int gn = n0 + r0 + l15; if (gn > N_ - 1) gn = N_ - 1;
        const __hip_bfloat16* qrow = qkv + (rowbase + gn) * 768;
        #pragma unroll
        for (int h = 0; h < 8; ++h) {
            short8 af = *(const short8*)&qrow[h * 32 + lq * 8];
            #pragma unroll
            for (int half = 0; half < 2; ++half) {
                short8 bfr = *(const short8*)&kvl[h * 1024 + (half * 16 + l15) * 32 + lq * 8];
                f32x4 acc = {};
                acc = __builtin_amdgcn_mfma_f32_16x16x32_bf16(af, bfr, acc, 0, 0, 0);
                int col = h * 32 + half * 16 + l15;
                float vm = vmeanb[bt * 256 + col];
                #pragma unroll
                for (int j = 0; j < 4; ++j)
                    attn[r0 + lq * 4 + j][col] = __float2bfloat16(acc[j] + vm);
            }
        }
    }
    __syncthreads();

    {
        int tr = t >> 5;
        int c8 = (t & 31) * 8;
        float w0[8], w1_[8], w2_[8];
        #pragma unroll
        for (int u = 0; u < 8; ++u) {
            w0[u]  = rw[bt * 768 + (c8 + u) * 3 + 0];
            w1_[u] = rw[bt * 768 + (c8 + u) * 3 + 1];
            w2_[u] = rw[bt * 768 + (c8 + u) * 3 + 2];
        }
        int rbeg = tr * 8;
        if (rbeg < rows) {
            int rend = rbeg + 8; if (rend > rows) rend = rows;
            union U8 { short8 v; __hip_bfloat16 h[8]; };
            auto loadv = [&](int gn, float* dst) {
                if (gn >= 0 && gn < N_) {
                    U8 u; u.v = *(const short8*)&qkv[(rowbase + gn) * 768 + 512 + c8];
                    #pragma unroll
                    for (int uu = 0; uu < 8; ++uu) dst[uu] = __bfloat162float(u.h[uu]);
                } else {
                    #pragma unroll
                    for (int uu = 0; uu < 8; ++uu) dst[uu] = 0.0f;
                }
            };
            float vprev[8], vcur[8], vnext[8];
            loadv(n0 + rbeg - 1, vprev);
            loadv(n0 + rbeg, vcur);
            for (int r = rbeg; r < rend; ++r) {
                int gn = n0 + r;
                loadv(gn + 1, vnext);
                U8 at; at.v = *(const short8*)&attn[r][c8];
                U8 zv;
                #pragma unroll
                for (int u = 0; u < 8; ++u) {
                    float s = __bfloat162float(at.h[u]) + w0[u] * vprev[u]
                              + w1_[u] * vcur[u] + w2_[u] * vnext[u];
                    zv.h[u] = __float2bfloat16(s);
                }
                *(short8*)&Z[(rowbase + gn) * 256 + c8] = zv.v;
                #pragma unroll
                for (int u = 0; u < 8; ++u) { vprev[u] = vcur[u]; vcur[u] = vnext[u]; }
            }
        }
    }
}

// ---------------------------------------------------------------------------
extern "C" void kernel_launch(void* const* d_in, const int* in_sizes, int n_in,
                              void* d_out, int out_size, void* d_ws, size_t ws_size,
                              hipStream_t stream) {
    (void)in_sizes; (void)n_in; (void)out_size; (void)ws_size;
    const float* x  = (const float*)d_in[0];
    const float* Wq = (const float*)d_in[1];  const float* bq = (const float*)d_in[2];
    const float* Wk = (const float*)d_in[3];  const float* bk = (const float*)d_in[4];
    const float* Wv = (const float*)d_in[5];  const float* bv = (const float*)d_in[6];
    const float* Wo = (const float*)d_in[7];  const float* bo = (const float*)d_in[8];
    const float* w1 = (const float*)d_in[9];  const float* b1 = (const float*)d_in[10];
    const float* w2 = (const float*)d_in[11]; const float* b2 = (const float*)d_in[12];
    float* out = (float*)d_out;

    char* ws = (char*)d_ws;
    size_t off = 0;
    auto take = [&](size_t bytes) -> char* {
        char* p = ws + off;
        off = (off + bytes + 255) & ~(size_t)255;
        return p;
    };

    __hip_bfloat16* qkv   = (__hip_bfloat16*)take((size_t)MROWS * 768 * 2);
    __hip_bfloat16* xb    = (__hip_bfloat16*)take((size_t)MROWS * 256 * 2);
    __hip_bfloat16* Zbuf  = xb;  // alias: xb dead after gemm_qkv, reused for Z
    __hip_bfloat16* wqkv  = (__hip_bfloat16*)take(768 * 256 * 2);
    __hip_bfloat16* wo    = (__hip_bfloat16*)take(256 * 256 * 2);
    float* bqkv   = (float*)take(768 * 4);
    float* msum   = (float*)take(384 * 256 * 4);
    float* rw     = (float*)take(384 * 768 * 4);
    __hip_bfloat16* kv2t = (__hip_bfloat16*)take((size_t)384 * 8192 * 2);
    float* vmeanb = (float*)take(384 * 256 * 4);

    hipMemsetAsync(msum, 0, 384 * 256 * 4, stream);

    prep_weights<<<768, 256, 0, stream>>>(Wq, bq, Wk, bk, Wv, bv, Wo, wqkv, bqkv, wo);
    convert_x<<<dim3(384, 4), 256, 0, stream>>>(x, xb, msum);
    mlp_rw<<<384, 256, 0, stream>>>(msum, w1, b1, w2, b2, rw);
    // QKV projection: [274944,256] x [768,256]^T -> bf16 qkv, bias fused
    gemm_qkv<<<256, 512, 0, stream>>>(xb, wqkv, bqkv, qkv);
    reduce_kv<<<384, 512, 0, stream>>>(qkv, kv2t, vmeanb);
    fuse_z2<<<dim3(384, 12), 256, 0, stream>>>(qkv, kv2t, vmeanb, rw, Zbuf);
    // Output projection: [274944,256] x [256,256]^T -> f32 out, bias fused
    gemm_out<<<256, 512, 0, stream>>>(Zbuf, wo, bo, out);
}

// Round 11
// 686.145 us; speedup vs baseline: 1.7657x; 1.7657x over previous
//
#include <hip/hip_runtime.h>
#include <hip/hip_bf16.h>
#include <math.h>

typedef __attribute__((ext_vector_type(8))) short short8;
typedef __attribute__((ext_vector_type(4))) short sv4;
typedef __attribute__((ext_vector_type(4))) float f32x4;
typedef unsigned int u32;

#define BT_ 384
#define N_ 716
#define C_ 256
#define H_ 8
#define D_ 32
#define MROWS (BT_ * N_)   /* 274944 */
#define NT_ (MROWS / 64)   /* 4296 row-tiles of 64 */
#define SCALE_ 0.17677669529663687f  /* 32^-0.5 */
#define INVN_ (1.0f / 716.0f)

__device__ __forceinline__ void gload_lds16(const void* g, void* l) {
    __builtin_amdgcn_global_load_lds(
        (const __attribute__((address_space(1))) u32*)g,
        (__attribute__((address_space(3))) u32*)l, 16, 0, 0);
}

// ---------------------------------------------------------------------------
// Assemble bf16 weight matrices + fused qkv bias. Wqkv_b[768][256], Wo_b[256][256]
// ---------------------------------------------------------------------------
__global__ void prep_weights(const float* __restrict__ Wq, const float* __restrict__ bq,
                             const float* __restrict__ Wk, const float* __restrict__ bk,
                             const float* __restrict__ Wv, const float* __restrict__ bv,
                             const float* __restrict__ Wo,
                             __hip_bfloat16* __restrict__ wqkv, float* __restrict__ bqkv,
                             __hip_bfloat16* __restrict__ wo) {
    int idx = blockIdx.x * 256 + threadIdx.x;
    if (idx < 768 * 256) {
        int o = idx >> 8, c = idx & 255;
        const float* W = (o < 256) ? Wq : ((o < 512) ? Wk : Wv);
        int oo = o & 255;
        wqkv[idx] = __float2bfloat16(W[oo * 256 + c]);
    }
    if (idx < 256 * 256) wo[idx] = __float2bfloat16(Wo[idx]);
    if (idx < 768) bqkv[idx] = (idx < 256) ? bq[idx] : ((idx < 512) ? bk[idx - 256] : bv[idx - 512]);
}

// ---------------------------------------------------------------------------
// x fp32 -> bf16 (vectorized float4/short4), plus per-(bt,channel) col sums
// grid (384, 4), block 256.
// ---------------------------------------------------------------------------
__global__ __launch_bounds__(256)
void convert_x(const float* __restrict__ x, __hip_bfloat16* __restrict__ xb,
               float* __restrict__ msum) {
    int bt = blockIdx.x, chunk = blockIdx.y;
    int t = threadIdx.x;
    int c4 = (t & 63) * 4;
    int r0 = t >> 6;
    size_t base = ((size_t)bt * N_ + (size_t)chunk * 179) * C_;
    float s0 = 0.f, s1 = 0.f, s2 = 0.f, s3 = 0.f;
    for (int r = r0; r < 179; r += 4) {
        float4 f = *(const float4*)&x[base + (size_t)r * C_ + c4];
        union { sv4 v; __hip_bfloat16 h[4]; } u;
        u.h[0] = __float2bfloat16(f.x);
        u.h[1] = __float2bfloat16(f.y);
        u.h[2] = __float2bfloat16(f.z);
        u.h[3] = __float2bfloat16(f.w);
        *(sv4*)&xb[base + (size_t)r * C_ + c4] = u.v;
        s0 += f.x; s1 += f.y; s2 += f.z; s3 += f.w;
    }
    atomicAdd(&msum[bt * C_ + c4 + 0], s0);
    atomicAdd(&msum[bt * C_ + c4 + 1], s1);
    atomicAdd(&msum[bt * C_ + c4 + 2], s2);
    atomicAdd(&msum[bt * C_ + c4 + 3], s3);
}

// ---------------------------------------------------------------------------
// Grouped 2-layer MLP -> per-channel 3-tap conv weights rw[bt][768]
// ---------------------------------------------------------------------------
__global__ __launch_bounds__(256)
void mlp_rw(const float* __restrict__ msum, const float* __restrict__ w1,
            const float* __restrict__ b1, const float* __restrict__ w2,
            const float* __restrict__ b2, float* __restrict__ rw) {
    int bt = blockIdx.x;
    int t = threadIdx.x;
    __shared__ float m_l[256];
    __shared__ float h1_l[256];
    m_l[t] = msum[bt * 256 + t] * INVN_;
    __syncthreads();
    int g = t >> 5;
    float a = b1[t];
    #pragma unroll
    for (int i = 0; i < 32; ++i) a += m_l[g * 32 + i] * w1[t * 32 + i];
    h1_l[t] = 0.5f * a * (1.0f + erff(a * 0.70710678118654752f));
    __syncthreads();
    for (int o = t; o < 768; o += 256) {
        int gg = o / 96;
        float s = b2[o];
        #pragma unroll
        for (int i = 0; i < 32; ++i) s += h1_l[gg * 32 + i] * w2[o * 32 + i];
        rw[bt * 768 + o] = s;
    }
}

// ---------------------------------------------------------------------------
// Persistent GEMM v3: single 32KB A-buffer, 4 blocks/CU (16 waves), direct
// stores from acc (static indices only), 2 barriers/tile. B reloaded per
// K-half from L2 (bf[2][4] = 32 VGPR). XCD-aware grid: all col-blocks of a
// stripe on one XCD. grid GRIDX*256 (1D), block 256 (4 waves, 64x32/wave).
// ---------------------------------------------------------------------------
template<int NCOLS, int GRIDX, bool OUT_BF16>
__global__ __launch_bounds__(256, 4)
void gemm_persist(const __hip_bfloat16* __restrict__ A, const __hip_bfloat16* __restrict__ Bm,
                  const float* __restrict__ bias, void* __restrict__ outp) {
    __shared__ __align__(16) __hip_bfloat16 As[64 * 256];   // 32 KB
    const int L = blockIdx.x;
    const int xcd = L & 7, w = L >> 3;
    const int cb = w % GRIDX;
    const int ib = xcd * 32 + w / GRIDX;    // stripe 0..255
    const int tid = threadIdx.x;
    const int lane = tid & 63;
    const int wave = tid >> 6;       // 0..3
    const int wn = wave;             // 32-col quarter
    const int colBase = cb * 128;
    const int l15 = lane & 15, lq = lane >> 4;
    const int lrow2 = lane >> 5;     // 0/1
    const int p = lane & 31;

    auto stageA = [&](int rt) {
        #pragma unroll
        for (int i = 0; i < 8; ++i) {
            int r = wave * 16 + 2 * i + lrow2;
            const __hip_bfloat16* g = A + ((size_t)rt * 64 + r) * 256 + ((p ^ (r & 7)) * 8);
            gload_lds16(g, &As[(wave * 16 + 2 * i) * 256]);
        }
    };

    const __hip_bfloat16* Bbase = Bm + (size_t)(colBase + wn * 32 + l15) * 256 + lq * 8;
    float biasr[2];
    #pragma unroll
    for (int n = 0; n < 2; ++n)
        biasr[n] = bias[colBase + wn * 32 + n * 16 + l15];

    stageA(ib);

    for (int rt = ib; rt < NT_; rt += 256) {
        asm volatile("s_waitcnt vmcnt(0)" ::: "memory");   // stage landed (+ prev stores drained)
        __builtin_amdgcn_s_barrier();

        f32x4 acc[4][2] = {};
        #pragma unroll
        for (int half = 0; half < 2; ++half) {
            short8 bfr[2][4];
            #pragma unroll
            for (int n = 0; n < 2; ++n)
                #pragma unroll
                for (int k2 = 0; k2 < 4; ++k2)
                    bfr[n][k2] = *(const short8*)(Bbase + (size_t)n * 16 * 256 + (half * 4 + k2) * 32);
            #pragma unroll
            for (int k2 = 0; k2 < 4; ++k2) {
                int ks = half * 4 + k2;
                short8 af[4];
                #pragma unroll
                for (int m = 0; m < 4; ++m) {
                    int row = m * 16 + l15;
                    af[m] = *(const short8*)&As[row * 256 + (((ks * 4 + lq) ^ (row & 7)) * 8)];
                }
                #pragma unroll
                for (int m = 0; m < 4; ++m)
                    #pragma unroll
                    for (int n = 0; n < 2; ++n)
                        acc[m][n] = __builtin_amdgcn_mfma_f32_16x16x32_bf16(af[m], bfr[n][k2], acc[m][n], 0, 0, 0);
            }
        }
        asm volatile("s_waitcnt lgkmcnt(0)" ::: "memory");
        __builtin_amdgcn_s_barrier();                      // As free for restage

        if (rt + 256 < NT_) stageA(rt + 256);

        // direct stores, all indices static (rule #20 safe)
        #pragma unroll
        for (int m = 0; m < 4; ++m)
            #pragma unroll
            for (int n = 0; n < 2; ++n) {
                int col = colBase + wn * 32 + n * 16 + l15;
                #pragma unroll
                for (int j = 0; j < 4; ++j) {
                    size_t row = (size_t)rt * 64 + m * 16 + lq * 4 + j;
                    float val = acc[m][n][j] + biasr[n];
                    if (OUT_BF16)
                        ((__hip_bfloat16*)outp)[row * NCOLS + col] = __float2bfloat16(val);
                    else
                        ((float*)outp)[row * NCOLS + col] = val;
                }
            }
    }
}

// ---------------------------------------------------------------------------
// MFMA reduce_kv (unchanged from R8/R9): one block per bt, 8 waves = 8 heads.
// ---------------------------------------------------------------------------
__global__ __launch_bounds__(512, 2)
void reduce_kv(const __hip_bfloat16* __restrict__ qkv, __hip_bfloat16* __restrict__ kv2t,
               float* __restrict__ vmeanb) {
    __shared__ __align__(16) __hip_bfloat16 T[512 * 64];   // 64 KB
    const int bt = blockIdx.x;
    const int tid = threadIdx.x;
    const int lane = tid & 63;
    const int h = tid >> 6;
    const int l15 = lane & 15, lq = lane >> 4;
    const int co = tid >> 3;
    const int np3 = tid & 7;
    const size_t rowbase = (size_t)bt * N_;

    union S8 { short8 v; unsigned short u[8]; };
    const short8 zero8 = {0, 0, 0, 0, 0, 0, 0, 0};

    auto issue_loads = [&](int n0, S8* Aq, S8* Bq) {
        #pragma unroll
        for (int s = 0; s < 4; ++s) {
            int n = n0 + 2 * (np3 + 8 * s);
            Aq[s].v = (n < N_)     ? *(const short8*)&qkv[(rowbase + n) * 768 + 256 + co * 8] : zero8;
            Bq[s].v = (n + 1 < N_) ? *(const short8*)&qkv[(rowbase + n + 1) * 768 + 256 + co * 8] : zero8;
        }
    };
    auto write_lds = [&](S8* Aq, S8* Bq) {
        #pragma unroll
        for (int s = 0; s < 4; ++s) {
            int r = 2 * (np3 + 8 * s);
            int slotbase = ((r >> 3));
            #pragma unroll
            for (int j = 0; j < 8; ++j) {
                int c = co * 8 + j;
                u32 wv = (u32)Aq[s].u[j] | ((u32)Bq[s].u[j] << 16);
                int off = c * 64 + ((slotbase ^ (c & 7)) << 3) + (r & 7);
                *(u32*)&T[off] = wv;
            }
        }
    };

    S8 bufA[4], bufB[4], nxtA[4], nxtB[4];
    issue_loads(0, bufA, bufB);

    f32x4 acc[2][2] = {};
    f32x4 acck[2] = {};
    f32x4 accv[2] = {};
    S8 ones;
    #pragma unroll
    for (int j = 0; j < 8; ++j) ones.u[j] = 0x3F80;   // bf16 1.0

    for (int chunk = 0; chunk < 12; ++chunk) {
        if (chunk < 11) issue_loads((chunk + 1) * 64, nxtA, nxtB);
        write_lds(bufA, bufB);
        __syncthreads();
        #pragma unroll
        for (int nc = 0; nc < 2; ++nc) {
            short8 af[2], bfr[2];
            int slot = nc * 4 + lq;
            #pragma unroll
            for (int dh = 0; dh < 2; ++dh) {
                int c = h * 32 + dh * 16 + l15;
                af[dh] = *(const short8*)&T[c * 64 + ((slot ^ (c & 7)) << 3)];
            }
            #pragma unroll
            for (int eh = 0; eh < 2; ++eh) {
                int c = 256 + h * 32 + eh * 16 + l15;
                bfr[eh] = *(const short8*)&T[c * 64 + ((slot ^ (c & 7)) << 3)];
            }
            #pragma unroll
            for (int dh = 0; dh < 2; ++dh)
                #pragma unroll
                for (int eh = 0; eh < 2; ++eh)
                    acc[dh][eh] = __builtin_amdgcn_mfma_f32_16x16x32_bf16(af[dh], bfr[eh], acc[dh][eh], 0, 0, 0);
            #pragma unroll
            for (int dh = 0; dh < 2; ++dh)
                acck[dh] = __builtin_amdgcn_mfma_f32_16x16x32_bf16(af[dh], ones.v, acck[dh], 0, 0, 0);
            #pragma unroll
            for (int eh = 0; eh < 2; ++eh)
                accv[eh] = __builtin_amdgcn_mfma_f32_16x16x32_bf16(ones.v, bfr[eh], accv[eh], 0, 0, 0);
        }
        __syncthreads();
        #pragma unroll
        for (int s = 0; s < 4; ++s) { bufA[s] = nxtA[s]; bufB[s] = nxtB[s]; }
    }

    const int bh = bt * 8 + h;
    #pragma unroll
    for (int eh = 0; eh < 2; ++eh) {
        int e = eh * 16 + l15;
        float vme = accv[eh][0] * INVN_;
        #pragma unroll
        for (int dh = 0; dh < 2; ++dh) {
            union { sv4 v; __hip_bfloat16 x[4]; } o;
            #pragma unroll
            for (int j = 0; j < 4; ++j) {
                float km = acck[dh][j] * INVN_;
                float val = acc[dh][eh][j] * (SCALE_ * INVN_) - SCALE_ * km * vme;
                o.x[j] = __float2bfloat16(val);
            }
            *(sv4*)&kv2t[(size_t)bh * 1024 + e * 32 + dh * 16 + lq * 4] = o.v;
        }
        if (lq == 0) vmeanb[bh * 32 + e] = vme;
    }
}

// ---------------------------------------------------------------------------
// fuse_z2 (unchanged from R9)
// ---------------------------------------------------------------------------
__global__ __launch_bounds__(256)
void fuse_z2(const __hip_bfloat16* __restrict__ qkv, const __hip_bfloat16* __restrict__ kv2t,
             const float* __restrict__ vmeanb, const float* __restrict__ rw,
             __hip_bfloat16* __restrict__ Z) {
    __shared__ __align__(16) __hip_bfloat16 attn[64][256];
    __shared__ __align__(16) __hip_bfloat16 kvl[8192];
    int bt = blockIdx.x;
    int n0 = blockIdx.y * 64;
    int rows = (N_ - n0 < 64) ? (N_ - n0) : 64;
    int t = threadIdx.x;
    const size_t rowbase = (size_t)bt * N_;

    {
        const __hip_bfloat16* src = kv2t + (size_t)bt * 8192;
        #pragma unroll
        for (int i = 0; i < 4; ++i) {
            int off = (t + i * 256) * 8;
            *(short8*)&kvl[off] = *(const short8*)&src[off];
        }
    }
    __syncthreads();

    {
        int lane = t & 63, wave = t >> 6;
        int l15 = lane & 15, lq = lane >> 4;
        int r0 = wave * 16;
        int gn = n0 + r0 + l15; if (gn > N_ - 1) gn = N_ - 1;
        const __hip_bfloat16* qrow = qkv + (rowbase + gn) * 768;
        #pragma unroll
        for (int h = 0; h < 8; ++h) {
            short8 af = *(const short8*)&qrow[h * 32 + lq * 8];
            #pragma unroll
            for (int half = 0; half < 2; ++half) {
                short8 bfr = *(const short8*)&kvl[h * 1024 + (half * 16 + l15) * 32 + lq * 8];
                f32x4 acc = {};
                acc = __builtin_amdgcn_mfma_f32_16x16x32_bf16(af, bfr, acc, 0, 0, 0);
                int col = h * 32 + half * 16 + l15;
                float vm = vmeanb[bt * 256 + col];
                #pragma unroll
                for (int j = 0; j < 4; ++j)
                    attn[r0 + lq * 4 + j][col] = __float2bfloat16(acc[j] + vm);
            }
        }
    }
    __syncthreads();

    {
        int tr = t >> 5;
        int c8 = (t & 31) * 8;
        float w0[8], w1_[8], w2_[8];
        #pragma unroll
        for (int u = 0; u < 8; ++u) {
            w0[u]  = rw[bt * 768 + (c8 + u) * 3 + 0];
            w1_[u] = rw[bt * 768 + (c8 + u) * 3 + 1];
            w2_[u] = rw[bt * 768 + (c8 + u) * 3 + 2];
        }
        int rbeg = tr * 8;
        if (rbeg < rows) {
            int rend = rbeg + 8; if (rend > rows) rend = rows;
            union U8 { short8 v; __hip_bfloat16 h[8]; };
            auto loadv = [&](int gn, float* dst) {
                if (gn >= 0 && gn < N_) {
                    U8 u; u.v = *(const short8*)&qkv[(rowbase + gn) * 768 + 512 + c8];
                    #pragma unroll
                    for (int uu = 0; uu < 8; ++uu) dst[uu] = __bfloat162float(u.h[uu]);
                } else {
                    #pragma unroll
                    for (int uu = 0; uu < 8; ++uu) dst[uu] = 0.0f;
                }
            };
            float vprev[8], vcur[8], vnext[8];
            loadv(n0 + rbeg - 1, vprev);
            loadv(n0 + rbeg, vcur);
            for (int r = rbeg; r < rend; ++r) {
                int gn = n0 + r;
                loadv(gn + 1, vnext);
                U8 at; at.v = *(const short8*)&attn[r][c8];
                U8 zv;
                #pragma unroll
                for (int u = 0; u < 8; ++u) {
                    float s = __bfloat162float(at.h[u]) + w0[u] * vprev[u]
                              + w1_[u] * vcur[u] + w2_[u] * vnext[u];
                    zv.h[u] = __float2bfloat16(s);
                }
                *(short8*)&Z[(rowbase + gn) * 256 + c8] = zv.v;
                #pragma unroll
                for (int u = 0; u < 8; ++u) { vprev[u] = vcur[u]; vcur[u] = vnext[u]; }
            }
        }
    }
}

// ---------------------------------------------------------------------------
extern "C" void kernel_launch(void* const* d_in, const int* in_sizes, int n_in,
                              void* d_out, int out_size, void* d_ws, size_t ws_size,
                              hipStream_t stream) {
    (void)in_sizes; (void)n_in; (void)out_size; (void)ws_size;
    const float* x  = (const float*)d_in[0];
    const float* Wq = (const float*)d_in[1];  const float* bq = (const float*)d_in[2];
    const float* Wk = (const float*)d_in[3];  const float* bk = (const float*)d_in[4];
    const float* Wv = (const float*)d_in[5];  const float* bv = (const float*)d_in[6];
    const float* Wo = (const float*)d_in[7];  const float* bo = (const float*)d_in[8];
    const float* w1 = (const float*)d_in[9];  const float* b1 = (const float*)d_in[10];
    const float* w2 = (const float*)d_in[11]; const float* b2 = (const float*)d_in[12];
    float* out = (float*)d_out;

    char* ws = (char*)d_ws;
    size_t off = 0;
    auto take = [&](size_t bytes) -> char* {
        char* p = ws + off;
        off = (off + bytes + 255) & ~(size_t)255;
        return p;
    };

    __hip_bfloat16* qkv   = (__hip_bfloat16*)take((size_t)MROWS * 768 * 2);
    __hip_bfloat16* xb    = (__hip_bfloat16*)take((size_t)MROWS * 256 * 2);
    __hip_bfloat16* Zbuf  = xb;  // alias: xb dead after gemm_qkv, reused for Z
    __hip_bfloat16* wqkv  = (__hip_bfloat16*)take(768 * 256 * 2);
    __hip_bfloat16* wo    = (__hip_bfloat16*)take(256 * 256 * 2);
    float* bqkv   = (float*)take(768 * 4);
    float* msum   = (float*)take(384 * 256 * 4);
    float* rw     = (float*)take(384 * 768 * 4);
    __hip_bfloat16* kv2t = (__hip_bfloat16*)take((size_t)384 * 8192 * 2);
    float* vmeanb = (float*)take(384 * 256 * 4);

    hipMemsetAsync(msum, 0, 384 * 256 * 4, stream);

    prep_weights<<<768, 256, 0, stream>>>(Wq, bq, Wk, bk, Wv, bv, Wo, wqkv, bqkv, wo);
    convert_x<<<dim3(384, 4), 256, 0, stream>>>(x, xb, msum);
    mlp_rw<<<384, 256, 0, stream>>>(msum, w1, b1, w2, b2, rw);
    // QKV projection: [274944,256] x [768,256]^T -> bf16 qkv, bias fused
    gemm_persist<768, 6, true><<<1536, 256, 0, stream>>>(xb, wqkv, bqkv, qkv);
    reduce_kv<<<384, 512, 0, stream>>>(qkv, kv2t, vmeanb);
    fuse_z2<<<dim3(384, 12), 256, 0, stream>>>(qkv, kv2t, vmeanb, rw, Zbuf);
    // Output projection: [274944,256] x [256,256]^T -> f32 out, bias fused
    gemm_persist<256, 2, false><<<512, 256, 0, stream>>>(Zbuf, wo, bo, out);
}